// Round 7
// baseline (297.005 us; speedup 1.0000x reference)
//
#include <hip/hip_runtime.h>
#include <stdint.h>

#define H_ 192
#define W_ 192
#define C_ 64
#define EPS_F 1e-8f
#define TILE 16
#define RCH 256       // faces per raster chunk
#define NSLICE 4      // z-interleaved slices per tile
#define NBUCK 256
#define MAXCH 64      // max chunks (16384/256)
#define NTILE ((W_/TILE)*(H_/TILE))   // 144

typedef unsigned long long ull;

// Output layout (floats), concatenated in reference return order:
// feats (H*W*C) | p2f (H*W) | zbuf (H*W) | bary (H*W*3) | dists (H*W)
#define OFF_FEATS 0
#define OFF_P2F   (H_*W_*C_)
#define OFF_ZBUF  (OFF_P2F + H_*W_)
#define OFF_BARY  (OFF_ZBUF + H_*W_)
#define OFF_DIST  (OFF_BARY + H_*W_*3)

// IEEE-exact ops (block FMA contraction; match numpy float32 op-for-op)
__device__ __forceinline__ float xm(float a, float b){ return __fmul_rn(a,b); }
__device__ __forceinline__ float xa(float a, float b){ return __fadd_rn(a,b); }
__device__ __forceinline__ float xsb(float a, float b){ return __fsub_rn(a,b); }
__device__ __forceinline__ float xd(float a, float b){ return __fdiv_rn(a,b); }

__device__ __forceinline__ float pixcoord(int i, float dim){
    float t = xa(xm(2.0f, (float)i), 1.0f);
    return xsb(1.0f, xd(t, dim));
}

__device__ __forceinline__ int zbucket(float zmn){
    int b = (int)((zmn - 2.5f) * 128.0f);   // scene z in [2.5,4.5); clamp keeps soundness
    return max(0, min(NBUCK-1, b));
}
// sound lower bound on zmin of any face in bucket >= b (0.999 margin absorbs ulps)
__device__ __forceinline__ float bucket_lb(int b){
    return (b <= 0) ? 0.0f : xa(2.5f, xm((float)b, 0.0078125f));
}

// transform one vertex (bit-identical to reference: R_p/T_p, then perspective)
__device__ __forceinline__ float3 xform(const float* __restrict__ pos, int vi,
        const float* __restrict__ K, const float* __restrict__ RT){
    float p0 = pos[3*vi+0], p1 = pos[3*vi+1], p2 = pos[3*vi+2];
    const float sgn[3] = {-1.f, -1.f, 1.f};
    float vv[3];
    #pragma unroll
    for (int j=0;j<3;j++){
        float rp0 = xm(RT[j*4+0], sgn[j]);
        float rp1 = xm(RT[j*4+1], sgn[j]);
        float rp2 = xm(RT[j*4+2], sgn[j]);
        float s = xa(xa(xm(p0,rp0), xm(p1,rp1)), xm(p2,rp2));
        vv[j] = xa(s, xm(RT[j*4+3], sgn[j]));
    }
    float z = vv[2];
    const float scale = 96.0f;
    float fx = xd(K[0], scale);
    float fy = xd(K[4], scale);
    float p0x = -xd(xsb(K[2], 96.0f), scale);
    float p0y = -xd(xsb(K[5], 96.0f), scale);
    float xn = xa(xd(xm(fx, vv[0]), z), p0x);
    float yn = xa(xd(xm(fy, vv[1]), z), p0y);
    return make_float3(xn, yn, z);
}

// ---- kernel 1: keys init + hist2 zero + per-block zmin histogram rows ----
__global__ __launch_bounds__(256) void k_prep(const float* __restrict__ pos,
        const int* __restrict__ faces, const float* __restrict__ K,
        const float* __restrict__ RT, ull* __restrict__ keys,
        int* __restrict__ hist_part, int* __restrict__ hist2, int Fn){
    __shared__ int lh[NBUCK];
    int t = threadIdx.x, bi = blockIdx.x;
    int gtid = bi*256 + t;
    lh[t] = 0;
    // keys init: 36864 = 16384*2 + 4096
    if (gtid < H_*W_) keys[gtid] = 0xFFFFFFFFFFFFFFFFULL;
    int g2 = gtid + 16384; if (g2 < H_*W_) keys[g2] = 0xFFFFFFFFFFFFFFFFULL;
    int g3 = gtid + 32768; if (g3 < H_*W_) keys[g3] = 0xFFFFFFFFFFFFFFFFULL;
    if (gtid < NBUCK) hist2[gtid] = 0;
    __syncthreads();
    if (gtid < Fn){
        int i0 = faces[3*gtid+0], i1 = faces[3*gtid+1], i2 = faces[3*gtid+2];
        float3 v0 = xform(pos, i0, K, RT);
        float3 v1 = xform(pos, i1, K, RT);
        float3 v2 = xform(pos, i2, K, RT);
        float area = xsb(xm(xsb(v1.x,v0.x), xsb(v2.y,v0.y)), xm(xsb(v1.y,v0.y), xsb(v2.x,v0.x)));
        bool ok = (area > EPS_F) && (v0.z > 0.f) && (v1.z > 0.f) && (v2.z > 0.f);
        if (ok){
            float zmn = fminf(v0.z, fminf(v1.z, v2.z));
            atomicAdd(&lh[zbucket(zmn)], 1);
        }
    }
    __syncthreads();
    hist_part[bi*NBUCK + t] = lh[t];   // block owns its row: no pre-zero needed
}

// ---- kernel 2: reduce hist rows -> prefix; publish chunk_lb+alive; scatter ----
// record (16 floats): x0,y0,x1,y1 | x2,y2,z0,z1 | z2,ia,zmin,fidx | xmn,xmx,ymn,ymx
__global__ __launch_bounds__(256) void k_scatter(const float* __restrict__ pos,
        const int* __restrict__ faces, const float* __restrict__ K,
        const float* __restrict__ RT, const int* __restrict__ hist_part,
        int* __restrict__ hist2, float* __restrict__ srec,
        float* __restrict__ meta, int Fn, int nblk_prep){
    __shared__ int hcnt[NBUCK];
    __shared__ int incl_s[NBUCK];
    int t = threadIdx.x, bi = blockIdx.x;
    int sum = 0;
    for (int b = 0; b < nblk_prep; b++) sum += hist_part[b*NBUCK + t];
    hcnt[t] = sum;
    incl_s[t] = sum;
    __syncthreads();
    for (int off=1; off<NBUCK; off<<=1){
        int u = (t >= off) ? incl_s[t-off] : 0;
        __syncthreads();
        incl_s[t] += u;
        __syncthreads();
    }
    if (bi == 0){
        if (t < MAXCH){
            int p = t << 8;
            int lo = 0, hi = NBUCK-1;   // smallest bucket with incl > p
            while (lo < hi){ int mid = (lo+hi) >> 1; if (incl_s[mid] > p) hi = mid; else lo = mid+1; }
            meta[1 + t] = bucket_lb(lo);
        }
        if (t == 0) ((int*)meta)[0] = incl_s[NBUCK-1];   // alive
    }
    int f = bi*256 + t;
    if (f >= Fn) return;
    int i0 = faces[3*f+0], i1 = faces[3*f+1], i2 = faces[3*f+2];
    float3 v0 = xform(pos, i0, K, RT);
    float3 v1 = xform(pos, i1, K, RT);
    float3 v2 = xform(pos, i2, K, RT);
    float area = xsb(xm(xsb(v1.x,v0.x), xsb(v2.y,v0.y)), xm(xsb(v1.y,v0.y), xsb(v2.x,v0.x)));
    bool ok = (area > EPS_F) && (v0.z > 0.f) && (v1.z > 0.f) && (v2.z > 0.f);
    if (!ok) return;
    float zmn = fminf(v0.z, fminf(v1.z, v2.z));
    int b = zbucket(zmn);
    int excl = incl_s[b] - hcnt[b];
    int posn = excl + atomicAdd(&hist2[b], 1);
    if (posn >= Fn) return;   // safety for replay garbage
    float ia = xd(1.0f, area);
    float xmn = fminf(v0.x, fminf(v1.x, v2.x)) - 1e-4f;
    float xmx = fmaxf(v0.x, fmaxf(v1.x, v2.x)) + 1e-4f;
    float ymn = fminf(v0.y, fminf(v1.y, v2.y)) - 1e-4f;
    float ymx = fmaxf(v0.y, fmaxf(v1.y, v2.y)) + 1e-4f;
    float4* q = (float4*)(srec + (size_t)posn*16);
    q[0] = make_float4(v0.x, v0.y, v1.x, v1.y);
    q[1] = make_float4(v2.x, v2.y, v0.z, v1.z);
    q[2] = make_float4(v2.z, ia, zmn, __int_as_float(f));
    q[3] = make_float4(xmn, xmx, ymn, ymx);
}

// ---- kernel 3: z-ordered tiled raster (pdone wave-break, block-wide exit) ----
__global__ __launch_bounds__(256) void k_raster(const float* __restrict__ srec,
        const float* __restrict__ meta, ull* __restrict__ keys, int Fn){
    __shared__ float lf[RCH*16];
    __shared__ float chunk_lb[MAXCH];
    __shared__ int wcnt[4];
    int tid = threadIdx.x;
    int bi  = blockIdx.x;
    int slice = bi & (NSLICE-1);
    int tile  = bi >> 2;                  // NSLICE==4
    int tx = tile % (W_/TILE), ty = tile / (W_/TILE);
    if (tid < MAXCH) chunk_lb[tid] = meta[1 + tid];
    int alive = min(max(((const int*)meta)[0], 0), Fn);
    __syncthreads();

    int ix = tx*TILE + (tid & 15);
    int iy = ty*TILE + (tid >> 4);
    int pix = iy*W_ + ix;
    float px = pixcoord(ix, (float)W_);
    float py = pixcoord(iy, (float)H_);
    float tx_hi = pixcoord(tx*TILE,          (float)W_);
    float tx_lo = pixcoord(tx*TILE + TILE-1, (float)W_);
    float ty_hi = pixcoord(ty*TILE,          (float)H_);
    float ty_lo = pixcoord(ty*TILE + TILE-1, (float)H_);
    int lane = tid & 63, wv = tid >> 6;
    int nch = min((alive + RCH-1) >> 8, MAXCH);

    float zbest = INFINITY, zskip = INFINITY;
    int fbest = -1, lastpub = -1;
    bool pdone = false;

    for (int c = slice; c < nch; c += NSLICE){
        ull kk = __hip_atomic_load(&keys[pix], __ATOMIC_RELAXED, __HIP_MEMORY_SCOPE_AGENT);
        zskip = fminf(zskip, __uint_as_float((unsigned)(kk >> 32)));
        // block-wide exit: all remaining faces have zmin >= chunk_lb[c]
        int done = (xm(chunk_lb[c], 0.999f) >= zskip) ? 1 : 0;
        if (__syncthreads_and(done)) break;   // barrier also protects lf reuse

        int f = (c << 8) + tid;
        bool keep = false;
        float4 q0, q1, q2, q3;
        if (f < alive){
            const float4* g = (const float4*)(srec + (size_t)f*16);
            q0 = g[0]; q1 = g[1]; q2 = g[2]; q3 = g[3];
            keep = (q3.x <= tx_hi) && (q3.y >= tx_lo) && (q3.z <= ty_hi) && (q3.w >= ty_lo);
        }
        ull m = __ballot(keep);
        if (lane == 0) wcnt[wv] = __popcll(m);
        __syncthreads();
        int basec = 0;
        #pragma unroll
        for (int w2 = 0; w2 < 4; ++w2) if (w2 < wv) basec += wcnt[w2];
        if (keep){
            int posn = basec + __popcll(m & ((1ULL << lane) - 1ULL));
            float4* l = (float4*)(lf + posn*16);
            l[0] = q0; l[1] = q1; l[2] = q2; l[3] = q3;
        }
        int nsurv = wcnt[0] + wcnt[1] + wcnt[2] + wcnt[3];
        __syncthreads();

        for (int k = 0; k < nsurv; k++){
            if (__ballot(!pdone) == 0ull) break;   // whole wave converged
            if (!pdone){
                const float* r = lf + k*16;   // same addr all lanes -> LDS broadcast
                float zmn = r[10];
                float t = xm(zmn, 0.999f);
                if (t >= zskip){
                    // this face's bucket floor lower-bounds ALL remaining faces
                    if (xm(bucket_lb((int)((zmn - 2.5f)*128.0f)), 0.999f) >= zskip)
                        pdone = true;
                } else if (px >= r[12] && px <= r[13] && py >= r[14] && py <= r[15]){
                    float x0=r[0], y0=r[1], x1=r[2], y1=r[3], x2=r[4], y2=r[5];
                    float dx0=xsb(x0,px), dx1=xsb(x1,px), dx2=xsb(x2,px);
                    float dy0=xsb(y0,py), dy1=xsb(y1,py), dy2=xsb(y2,py);
                    float e0 = xsb(xm(dx1,dy2), xm(dy1,dx2));
                    float e1 = xsb(xm(dx2,dy0), xm(dy2,dx0));
                    float e2 = xsb(xm(dx0,dy1), xm(dy0,dx1));
                    if (e0 >= 0.f && e1 >= 0.f && e2 >= 0.f){
                        float z0=r[6], z1=r[7], z2=r[8], ia=r[9];
                        float w0 = xm(e0, ia), w1 = xm(e1, ia), w2 = xm(e2, ia);
                        float l0 = xm(xm(w0,z1),z2);
                        float l1 = xm(xm(z0,w1),z2);
                        float l2 = xm(xm(z0,z1),w2);
                        float s  = xa(xa(l0,l1),l2);
                        float dn = (s == 0.f) ? 1.0f : s;
                        float b0 = fmaxf(xd(l0,dn), 0.f);
                        float b1 = fmaxf(xd(l1,dn), 0.f);
                        float b2 = fmaxf(xd(l2,dn), 0.f);
                        float bs = fmaxf(xa(xa(b0,b1),b2), EPS_F);
                        b0 = xd(b0,bs); b1 = xd(b1,bs); b2 = xd(b2,bs);
                        float zp = xa(xa(xm(b0,z0),xm(b1,z1)),xm(b2,z2));
                        int fidx = __float_as_int(r[11]);
                        if (zp < zbest || (zp == zbest && fidx < fbest)){
                            zbest = zp; fbest = fidx;
                            zskip = fminf(zskip, zp);
                        }
                    }
                }
            }
        }
        if (fbest >= 0 && fbest != lastpub){
            ull key = (((ull)__float_as_uint(zbest)) << 32) | (unsigned)fbest;
            atomicMin(&keys[pix], key);
            lastpub = fbest;
        }
    }
}

// ---- kernel 4: resolve + shade, 16 lanes/pixel, float4 feature path ----
__global__ __launch_bounds__(256) void k_post(const ull* __restrict__ keys,
        const float* __restrict__ pos, const float* __restrict__ feats,
        const int* __restrict__ faces, const float* __restrict__ K,
        const float* __restrict__ RT, float* __restrict__ out){
    int t = threadIdx.x;
    int c4 = t & 15;                 // channel group (4 channels)
    int pix = blockIdx.x*16 + (t >> 4);
    float* p2f  = out + OFF_P2F;
    float* zbuf = out + OFF_ZBUF;
    float* bary = out + OFF_BARY;
    float* dist = out + OFF_DIST;
    ull key = keys[pix];
    if (key == 0xFFFFFFFFFFFFFFFFULL){
        ((float4*)(out + OFF_FEATS + pix*C_))[c4] = make_float4(0.f,0.f,0.f,0.f);
        if (c4 == 0){ p2f[pix] = -1.0f; zbuf[pix] = -1.0f; dist[pix] = -1.0f; }
        if (c4 < 3) bary[3*pix+c4] = -1.0f;
        return;
    }
    int f = (int)(key & 0xFFFFFFFFu);
    float z = __uint_as_float((unsigned)(key >> 32));
    int ix = pix % W_, iy = pix / W_;
    float px = pixcoord(ix, (float)W_);
    float py = pixcoord(iy, (float)H_);
    int i0 = faces[3*f+0], i1 = faces[3*f+1], i2 = faces[3*f+2];
    float3 v0 = xform(pos, i0, K, RT);
    float3 v1 = xform(pos, i1, K, RT);
    float3 v2 = xform(pos, i2, K, RT);
    float x0=v0.x, y0=v0.y, z0=v0.z;
    float x1=v1.x, y1=v1.y, z1=v1.z;
    float x2=v2.x, y2=v2.y, z2=v2.z;
    float area = xsb(xm(xsb(x1,x0), xsb(y2,y0)), xm(xsb(y1,y0), xsb(x2,x0)));
    float ia = xd(1.0f, area);   // winner is guaranteed a live face
    float w0 = xm(xsb(xm(xsb(x1,px),xsb(y2,py)), xm(xsb(y1,py),xsb(x2,px))), ia);
    float w1 = xm(xsb(xm(xsb(x2,px),xsb(y0,py)), xm(xsb(y2,py),xsb(x0,px))), ia);
    float w2 = xm(xsb(xm(xsb(x0,px),xsb(y1,py)), xm(xsb(y0,py),xsb(x1,px))), ia);
    float l0 = xm(xm(w0,z1),z2);
    float l1 = xm(xm(z0,w1),z2);
    float l2 = xm(xm(z0,z1),w2);
    float s  = xa(xa(l0,l1),l2);
    float dn = (s == 0.f) ? 1.0f : s;
    float b0 = fmaxf(xd(l0,dn), 0.f);
    float b1 = fmaxf(xd(l1,dn), 0.f);
    float b2 = fmaxf(xd(l2,dn), 0.f);
    float bs = fmaxf(xa(xa(b0,b1),b2), EPS_F);
    b0 = xd(b0,bs); b1 = xd(b1,bs); b2 = xd(b2,bs);
    float4 f0v = ((const float4*)(feats + (size_t)i0*C_))[c4];
    float4 f1v = ((const float4*)(feats + (size_t)i1*C_))[c4];
    float4 f2v = ((const float4*)(feats + (size_t)i2*C_))[c4];
    float4 res;
    res.x = xa(xa(xm(b0,f0v.x), xm(b1,f1v.x)), xm(b2,f2v.x));
    res.y = xa(xa(xm(b0,f0v.y), xm(b1,f1v.y)), xm(b2,f2v.y));
    res.z = xa(xa(xm(b0,f0v.z), xm(b1,f1v.z)), xm(b2,f2v.z));
    res.w = xa(xa(xm(b0,f0v.w), xm(b1,f1v.w)), xm(b2,f2v.w));
    ((float4*)(out + OFF_FEATS + pix*C_))[c4] = res;
    if (c4 == 0){ p2f[pix] = (float)f; zbuf[pix] = z; dist[pix] = 0.0f; }
    if (c4 < 3){
        float bb = (c4 == 0) ? b0 : ((c4 == 1) ? b1 : b2);
        bary[3*pix+c4] = bb;
    }
}

extern "C" void kernel_launch(void* const* d_in, const int* in_sizes, int n_in,
                              void* d_out, int out_size, void* d_ws, size_t ws_size,
                              hipStream_t stream) {
    const float* positions = (const float*)d_in[0];
    const float* features  = (const float*)d_in[1];
    const int*   faces     = (const int*)  d_in[2];
    const float* K         = (const float*)d_in[3];
    const float* RT        = (const float*)d_in[4];
    int Fn = in_sizes[2] / 3;   // 16384
    int nblk = (Fn + 255) / 256;  // 64

    float* srec      = (float*)d_ws;                      // Fn*16 floats
    ull*   keys      = (ull*)(srec + (size_t)Fn*16);      // H*W keys
    int*   hist_part = (int*)(keys + (size_t)H_*W_);      // nblk*256
    int*   hist2     = hist_part + nblk*NBUCK;            // 256
    float* meta      = (float*)(hist2 + NBUCK);           // [0]=alive(int), [1..64]=chunk_lb

    k_prep   <<<nblk, 256, 0, stream>>>(positions, faces, K, RT, keys, hist_part, hist2, Fn);
    k_scatter<<<nblk, 256, 0, stream>>>(positions, faces, K, RT, hist_part, hist2, srec, meta, Fn, nblk);
    k_raster <<<NTILE*NSLICE, 256, 0, stream>>>(srec, meta, keys, Fn);
    k_post   <<<(H_*W_)/16, 256, 0, stream>>>(keys, positions, features, faces, K, RT, (float*)d_out);
}